// Round 13
// baseline (359.017 us; speedup 1.0000x reference)
//
#include <hip/hip_runtime.h>
#include <math.h>

#define BB 256
#define SS 256
#define NH 4

typedef __attribute__((ext_vector_type(8))) short bfrag;   // 8 bf16 (4 VGPRs)
typedef __attribute__((ext_vector_type(4))) float ffrag;   // 4 fp32 acc

__device__ inline unsigned short f2bf(float x) {
    unsigned u = __float_as_uint(x);
    u += 0x7FFF + ((u >> 16) & 1);          // round-to-nearest-even
    return (unsigned short)(u >> 16);
}
__device__ inline float bf2f(unsigned short h) {
    return __uint_as_float(((unsigned)h) << 16);
}
// Bit-twiddled RNE pack (R4..R12-proven numerics).
__device__ inline unsigned pack2(float a, float b) {
    return (unsigned)f2bf(a) | ((unsigned)f2bf(b) << 16);
}
union FragU { unsigned u[4]; bfrag b; };

// ws layout (bf16 elements):
//   Xb  at 0         [B][S][128]   8388608
//   Wb  at 8388608   [512][128]      65536
//   Wob at 8454144   [128][128]      16384
//   og  at 8470528   [B][S][128]   8388608
#define XB_OFF  0
#define WB_OFF  8388608
#define WOB_OFF 8454144
#define OG_OFF  8470528

// ---------------------------------------------------------------------------
// k0: cast X, W_qkvg, W_o from fp32 to bf16 into workspace. 8 elems/thread.
// ---------------------------------------------------------------------------
__global__ __launch_bounds__(256) void k0_cast(
    const float* __restrict__ X, const float* __restrict__ W,
    const float* __restrict__ Wo, unsigned short* __restrict__ dst)
{
    const int gid = blockIdx.x * 256 + threadIdx.x;
    const int XN8 = 8388608 / 8, WN8 = 65536 / 8, WoN8 = 16384 / 8;
    const float* src;
    size_t soff, doff;
    if (gid < XN8)            { src = X;  soff = (size_t)gid * 8;                 doff = XB_OFF + soff; }
    else if (gid < XN8 + WN8) { src = W;  soff = (size_t)(gid - XN8) * 8;         doff = WB_OFF + soff; }
    else if (gid < XN8 + WN8 + WoN8) { src = Wo; soff = (size_t)(gid - XN8 - WN8) * 8; doff = WOB_OFF + soff; }
    else return;
    const float4 a = *(const float4*)(src + soff);
    const float4 b = *(const float4*)(src + soff + 4);
    unsigned r0 = pack2(a.x, a.y), r1 = pack2(a.z, a.w);
    unsigned r2 = pack2(b.x, b.y), r3 = pack2(b.z, b.w);
    uint4 o; o.x = r0; o.y = r1; o.z = r2; o.w = r3;
    *(uint4*)(dst + doff) = o;
}

// ---------------------------------------------------------------------------
// Fused QKVG projection + attention per (b,h). 256 thr = 4 waves; wave w owns
// s/q rows [64w, 64w+64). 16x16x32 bf16 MFMA layouts:
//   A/B-frag: row = lane&15, k = (lane>>4)*8 + j
//   C/D:      row = (lane>>4)*4 + reg, col = lane&15
//
// R13: Qb and Gb LDS ELIMINATED (they were intra-wave transpose engines).
//  - Q: SWAPPED projection mfma(W,X) -> Q^T C-layout (s in l15, c in
//    (quad,reg)). Under k-permutation pi(quad*8+j) = (j&4?16:0)+quad*4+(j&3)
//    (bijective; same algebra as R12's correctness-passed PV trick), the
//    S-MFMA B-frag is the lane's OWN registers (qscale folded at pack).
//    pi is absorbed on the K side: Kb stores column p(c) =
//    ((c&15)>>2)*8+(c&3)+((c>>4)<<2) (scalar stores as before; b128 reads
//    unchanged, 16B-aligned). S output layout is UNCHANGED.
//  - G: swapped mfma(Wg,X) -> G^T: lane holds exactly the og-epilogue's
//    G[q=..+l15][ch*16+quad*4+r] in its own registers. sigmoid in-register;
//    f2bf-pack / bf2f-unpack preserves R8 numerics bit-exactly.
// LDS: Kb 20480 + Vt 16896 + mask 1024 = 38400 B (37.5 KB) -> 3 blocks/CU.
// __launch_bounds__(256,3): 12 waves/CU -> 170-VGPR cap (both arg2 readings
// agree for 256-thr blocks); code needs ~160. PV keeps R0's proven shuffle
// form (R12 showed removing it hurts); V layout natural.
// ---------------------------------------------------------------------------
__global__ __launch_bounds__(256, 3) void k_fused(
    const unsigned short* __restrict__ Xb,   // bf16 [B][S][128]
    const unsigned short* __restrict__ Wb,   // bf16 [512][128]
    const float* __restrict__ gbias,         // [128]
    const float* __restrict__ mask,          // [B][S] (k-indexed)
    const float* __restrict__ bias,          // [NH][S][S]
    unsigned short* __restrict__ og)         // bf16 [B][S][128]
{
    const int h = blockIdx.x, b = blockIdx.y;
    const int t = threadIdx.x;
    const int w = t >> 6, lane = t & 63, l15 = lane & 15, quad = lane >> 4;

    __shared__ unsigned short Kb[SS * 40];   // [s][p(c)] stride 40 (pi-permuted cols)
    __shared__ unsigned short Vt[32 * 264];  // [c][s] stride 264
    __shared__ float maskLds[SS];

    maskLds[t] = (mask[b * SS + t] - 1.0f) * 1e9f;

    const float qscale = 0.17677669529663687f;  // 1/sqrt(32)

    // Per-st Q^T B-frags and packed G (named vars; all selects compile-time)
    FragU qa0, qa1, qa2, qa3;
    unsigned g0c0a, g0c0b, g0c1a, g0c1b;
    unsigned g1c0a, g1c0b, g1c1a, g1c1b;
    unsigned g2c0a, g2c0b, g2c1a, g2c1b;
    unsigned g3c0a, g3c0b, g3c1a, g3c1b;

    // ---------------- phase A: QKVG projection for head h ----------------
#pragma unroll
    for (int half = 0; half < 2; ++half) {
        bfrag Wfr[4][4];
#pragma unroll
        for (int f4 = 0; f4 < 4; ++f4) {
            const int floc = (half * 4 + f4) * 16 + l15;            // 0..127
            const int grow = (floc >> 5) * 128 + h * 32 + (floc & 31);
#pragma unroll
            for (int cc = 0; cc < 4; ++cc)
                Wfr[f4][cc] = *(const bfrag*)(Wb + grow * 128 + cc * 32 + quad * 8);
        }
#pragma unroll
        for (int st = 0; st < 4; ++st) {
            const int s = w * 64 + st * 16 + l15;
            bfrag Xfr[4];
#pragma unroll
            for (int cc = 0; cc < 4; ++cc)
                Xfr[cc] = *(const bfrag*)(Xb + (b * SS + s) * 128 + cc * 32 + quad * 8);
#pragma unroll
            for (int f4 = 0; f4 < 4; ++f4) {
                const int ft = half * 4 + f4;
                if (ft < 2) {
                    // ---- Q: swapped mfma -> Q^T (c rows = quad*4+r [+16])
                    ffrag D = {0.f, 0.f, 0.f, 0.f};
#pragma unroll
                    for (int cc = 0; cc < 4; ++cc)
                        D = __builtin_amdgcn_mfma_f32_16x16x32_bf16(Wfr[f4][cc], Xfr[cc], D, 0, 0, 0);
                    const unsigned lo = pack2(D[0] * qscale, D[1] * qscale);
                    const unsigned hi = pack2(D[2] * qscale, D[3] * qscale);
                    FragU* qa = (st == 0) ? &qa0 : (st == 1) ? &qa1 : (st == 2) ? &qa2 : &qa3;
                    if (ft == 0) { qa->u[0] = lo; qa->u[1] = hi; }
                    else         { qa->u[2] = lo; qa->u[3] = hi; }
                } else if (ft < 4) {
                    // ---- K: normal orientation; pi-permuted column store
                    ffrag D = {0.f, 0.f, 0.f, 0.f};
#pragma unroll
                    for (int cc = 0; cc < 4; ++cc)
                        D = __builtin_amdgcn_mfma_f32_16x16x32_bf16(Xfr[cc], Wfr[f4][cc], D, 0, 0, 0);
                    const int c = (ft - 2) * 16 + l15;               // 0..31
                    const int p = ((c & 15) >> 2) * 8 + (c & 3) + ((c >> 4) << 2);
                    const int srow0 = w * 64 + st * 16 + quad * 4;
#pragma unroll
                    for (int r = 0; r < 4; ++r)
                        Kb[(srow0 + r) * 40 + p] = f2bf(D[r]);
                } else if (ft < 6) {
                    // ---- V: normal orientation -> Vt [c][s] (R0 layout)
                    ffrag D = {0.f, 0.f, 0.f, 0.f};
#pragma unroll
                    for (int cc = 0; cc < 4; ++cc)
                        D = __builtin_amdgcn_mfma_f32_16x16x32_bf16(Xfr[cc], Wfr[f4][cc], D, 0, 0, 0);
                    const int fcol = ft * 16 + l15;
                    const int srow0 = w * 64 + st * 16 + quad * 4;
                    const int base = (fcol - 64) * 264 + srow0;
                    *(unsigned*)&Vt[base]     = pack2(D[0], D[1]);
                    *(unsigned*)&Vt[base + 2] = pack2(D[2], D[3]);
                } else {
                    // ---- G: swapped mfma -> G^T (c rows = ch*16+quad*4+r, s col = l15)
                    ffrag D = {0.f, 0.f, 0.f, 0.f};
#pragma unroll
                    for (int cc = 0; cc < 4; ++cc)
                        D = __builtin_amdgcn_mfma_f32_16x16x32_bf16(Wfr[f4][cc], Xfr[cc], D, 0, 0, 0);
                    const int ch = ft - 6;                           // 0,1
                    float gv[4];
#pragma unroll
                    for (int r = 0; r < 4; ++r) {
                        const float gb = gbias[h * 32 + ch * 16 + quad * 4 + r];
                        gv[r] = 1.0f / (1.0f + __expf(-(D[r] + gb)));
                    }
                    const unsigned pa = pack2(gv[0], gv[1]);
                    const unsigned pb = pack2(gv[2], gv[3]);
                    if (st == 0) { if (ch == 0) { g0c0a = pa; g0c0b = pb; } else { g0c1a = pa; g0c1b = pb; } }
                    if (st == 1) { if (ch == 0) { g1c0a = pa; g1c0b = pb; } else { g1c1a = pa; g1c1b = pb; } }
                    if (st == 2) { if (ch == 0) { g2c0a = pa; g2c0b = pb; } else { g2c1a = pa; g2c1b = pb; } }
                    if (st == 3) { if (ch == 0) { g3c0a = pa; g3c0b = pb; } else { g3c1a = pa; g3c1b = pb; } }
                }
            }
        }
    }
    __syncthreads();

    // ---------------- phase B: attention ----------------
    bfrag Vfr[2][8];   // A-frags of V^T, loop-invariant
#pragma unroll
    for (int ch = 0; ch < 2; ++ch)
#pragma unroll
        for (int ck = 0; ck < 8; ++ck)
            Vfr[ch][ck] = *(const bfrag*)&Vt[(ch * 16 + l15) * 264 + ck * 32 + quad * 8];

    const int srcA = l15 + ((quad & 1) * 2) * 16;
    const int srcB = srcA + 16;
    const bool hi = (quad >> 1) != 0;

    for (int qq = 0; qq < 4; ++qq) {
        const int q = w * 64 + qq * 16 + l15;
        // Q^T B-frag and G pairs from registers (wave-uniform select)
        bfrag Qfr;
        unsigned gc0a, gc0b, gc1a, gc1b;
        if (qq == 0)      { Qfr = qa0.b; gc0a = g0c0a; gc0b = g0c0b; gc1a = g0c1a; gc1b = g0c1b; }
        else if (qq == 1) { Qfr = qa1.b; gc0a = g1c0a; gc0b = g1c0b; gc1a = g1c1a; gc1b = g1c1b; }
        else if (qq == 2) { Qfr = qa2.b; gc0a = g2c0a; gc0b = g2c0b; gc1a = g2c1a; gc1b = g2c1b; }
        else              { Qfr = qa3.b; gc0a = g3c0a; gc0b = g3c0b; gc1a = g3c1a; gc1b = g3c1b; }

        ffrag S[16];
#pragma unroll
        for (int kt = 0; kt < 16; ++kt) {
            const bfrag Kfr = *(const bfrag*)&Kb[(kt * 16 + l15) * 40 + quad * 8];
            const ffrag z = {0.f, 0.f, 0.f, 0.f};
            S[kt] = __builtin_amdgcn_mfma_f32_16x16x32_bf16(Kfr, Qfr, z, 0, 0, 0);
        }

        // + bias + mask; running max (lane owns column q; rows k=kt*16+quad*4+r)
        const float* brow = bias + (h * SS + q) * SS;
        float m = -1e30f;
#pragma unroll
        for (int kt = 0; kt < 16; ++kt) {
            const float4 bv = *(const float4*)(brow + kt * 16 + quad * 4);
            const float4 mv = *(const float4*)(maskLds + kt * 16 + quad * 4);
            S[kt][0] += bv.x + mv.x; S[kt][1] += bv.y + mv.y;
            S[kt][2] += bv.z + mv.z; S[kt][3] += bv.w + mv.w;
            m = fmaxf(m, fmaxf(fmaxf(S[kt][0], S[kt][1]), fmaxf(S[kt][2], S[kt][3])));
        }
        m = fmaxf(m, __shfl_xor(m, 16, 64));
        m = fmaxf(m, __shfl_xor(m, 32, 64));

        float l = 0.f;
        unsigned pk[16][2];   // P packed bf16 pairs (r01, r23), C-layout
#pragma unroll
        for (int kt = 0; kt < 16; ++kt) {
            const float p0 = __expf(S[kt][0] - m);
            const float p1 = __expf(S[kt][1] - m);
            const float p2 = __expf(S[kt][2] - m);
            const float p3 = __expf(S[kt][3] - m);
            l += (p0 + p1) + (p2 + p3);
            pk[kt][0] = pack2(p0, p1);
            pk[kt][1] = pack2(p2, p3);
        }
        l += __shfl_xor(l, 16, 64);
        l += __shfl_xor(l, 32, 64);

        // C-layout -> B-frag transform via cross-quad shuffles (R0-proven).
        ffrag O[2];
        O[0] = (ffrag){0.f, 0.f, 0.f, 0.f};
        O[1] = (ffrag){0.f, 0.f, 0.f, 0.f};
#pragma unroll
        for (int ck = 0; ck < 8; ++ck) {
            const unsigned a0 = (unsigned)__shfl((int)pk[2 * ck][0],     srcA, 64);
            const unsigned b0 = (unsigned)__shfl((int)pk[2 * ck + 1][0], srcA, 64);
            const unsigned a1 = (unsigned)__shfl((int)pk[2 * ck][1],     srcA, 64);
            const unsigned b1 = (unsigned)__shfl((int)pk[2 * ck + 1][1], srcA, 64);
            const unsigned a2 = (unsigned)__shfl((int)pk[2 * ck][0],     srcB, 64);
            const unsigned b2 = (unsigned)__shfl((int)pk[2 * ck + 1][0], srcB, 64);
            const unsigned a3 = (unsigned)__shfl((int)pk[2 * ck][1],     srcB, 64);
            const unsigned b3 = (unsigned)__shfl((int)pk[2 * ck + 1][1], srcB, 64);
            FragU fu;
            fu.u[0] = hi ? b0 : a0;
            fu.u[1] = hi ? b1 : a1;
            fu.u[2] = hi ? b2 : a2;
            fu.u[3] = hi ? b3 : a3;
            O[0] = __builtin_amdgcn_mfma_f32_16x16x32_bf16(Vfr[0][ck], fu.b, O[0], 0, 0, 0);
            O[1] = __builtin_amdgcn_mfma_f32_16x16x32_bf16(Vfr[1][ck], fu.b, O[1], 0, 0, 0);
        }

        const float invl = 1.0f / l;
        unsigned* orow = (unsigned*)(og + (b * SS + q) * 128 + h * 32);
#pragma unroll
        for (int ch = 0; ch < 2; ++ch) {
            const unsigned ga = ch ? gc1a : gc0a;
            const unsigned gb2 = ch ? gc1b : gc0b;
            const int c0 = ch * 16 + quad * 4;
            const float v0 = O[ch][0] * invl * bf2f((unsigned short)(ga & 0xffff));
            const float v1 = O[ch][1] * invl * bf2f((unsigned short)(ga >> 16));
            const float v2 = O[ch][2] * invl * bf2f((unsigned short)(gb2 & 0xffff));
            const float v3 = O[ch][3] * invl * bf2f((unsigned short)(gb2 >> 16));
            orow[(c0 >> 1) + 0] = pack2(v0, v1);
            orow[(c0 >> 1) + 1] = pack2(v2, v3);
        }
    }
}

// ---------------------------------------------------------------------------
// k3: out[(s*B + j)*128 + c] = addt[same] + bo[c] + sum_f og[j][s][f]*Wo[c][f]
// R8-passed version: block (j, ih) = 64 s-rows, grid (256,4); og staging
// coalesced; MFMA -> fp32 LDS; coalesced float4 epilogue (half-wave per row).
// ---------------------------------------------------------------------------
__global__ __launch_bounds__(256) void k3_proj(
    const unsigned short* __restrict__ ogb,  // bf16 [B(j)][S(s)][128]
    const unsigned short* __restrict__ Wob,  // bf16 [128][128]
    const float* __restrict__ bo,            // [128]
    const float* __restrict__ addt,          // [S][B][128] view
    float* __restrict__ out)                 // [S][B][128]
{
    const int j = blockIdx.x, ih = blockIdx.y;   // ih: s-chunk of 64 rows
    const int t = threadIdx.x;
    const int w = t >> 6, lane = t & 63, l15 = lane & 15, quad = lane >> 4;

    __shared__ unsigned short OgS[64 * 136];  // [s_loc][f] stride 136, 17.4 KB
    __shared__ float OutS[64 * 132];          // [s_loc][c] stride 132, 33.8 KB

    // stage og[j][ih*64 + ss][0..128) -> LDS (coalesced; 4 threads per row)
    {
        const int ss = t >> 2;                // 0..63
        const int c32 = (t & 3) * 32;         // 0,32,64,96
        const unsigned short* src = ogb + (((size_t)j * SS + ih * 64 + ss) * 128) + c32;
        unsigned short* dst = &OgS[ss * 136 + c32];
#pragma unroll
        for (int u = 0; u < 4; ++u)
            *(uint4*)(dst + u * 8) = *(const uint4*)(src + u * 8);
    }

    // per-wave Wo B-frags: c rows (w*2+ctl)*16 + l15
    bfrag Wfr[2][4];
#pragma unroll
    for (int ctl = 0; ctl < 2; ++ctl) {
        const int crow = (w * 2 + ctl) * 16 + l15;
#pragma unroll
        for (int cc = 0; cc < 4; ++cc)
            Wfr[ctl][cc] = *(const bfrag*)(Wob + crow * 128 + cc * 32 + quad * 8);
    }
    const float bo0 = bo[(w * 2 + 0) * 16 + l15];
    const float bo1 = bo[(w * 2 + 1) * 16 + l15];

    __syncthreads();

#pragma unroll
    for (int jt = 0; jt < 4; ++jt) {
        bfrag Ab[4];
#pragma unroll
        for (int cc = 0; cc < 4; ++cc)
            Ab[cc] = *(const bfrag*)&OgS[(jt * 16 + l15) * 136 + cc * 32 + quad * 8];

        ffrag D0 = {0.f, 0.f, 0.f, 0.f};
        ffrag D1 = {0.f, 0.f, 0.f, 0.f};
#pragma unroll
        for (int cc = 0; cc < 4; ++cc) {
            D0 = __builtin_amdgcn_mfma_f32_16x16x32_bf16(Ab[cc], Wfr[0][cc], D0, 0, 0, 0);
            D1 = __builtin_amdgcn_mfma_f32_16x16x32_bf16(Ab[cc], Wfr[1][cc], D1, 0, 0, 0);
        }

        // D (+bo) -> LDS; C/D layout: row = quad*4+r (within 16), col = l15
        const int c0 = (w * 2 + 0) * 16 + l15;
        const int c1 = (w * 2 + 1) * 16 + l15;
#pragma unroll
        for (int r = 0; r < 4; ++r) {
            const int row = jt * 16 + quad * 4 + r;
            OutS[row * 132 + c0] = D0[r] + bo0;
            OutS[row * 132 + c1] = D1[r] + bo1;
        }
    }
    __syncthreads();

    // coalesced epilogue: half-wave per s-row, float4 ld/add/st
    {
        const int c4 = lane & 31;             // float4 index within the row
        const int rsub = t >> 5;              // 0..7 (wave, half)
#pragma unroll
        for (int v = 0; v < 8; ++v) {
            const int row = v * 8 + rsub;     // 0..63
            const int s = ih * 64 + row;
            const size_t off = ((size_t)s * BB + j) * 128 + c4 * 4;
            const float4 av = *(const float4*)(addt + off);
            const float4 dv = *(const float4*)&OutS[row * 132 + c4 * 4];
            float4 ov;
            ov.x = dv.x + av.x; ov.y = dv.y + av.y;
            ov.z = dv.z + av.z; ov.w = dv.w + av.w;
            *(float4*)(out + off) = ov;
        }
    }
}

extern "C" void kernel_launch(void* const* d_in, const int* in_sizes, int n_in,
                              void* d_out, int out_size, void* d_ws, size_t ws_size,
                              hipStream_t stream) {
    const float* X     = (const float*)d_in[0];  // input_qkv [1,256,256,128]
    const float* mask  = (const float*)d_in[1];  // [1,256,1,1,256]
    const float* bias  = (const float*)d_in[2];  // [1,1,4,256,256]
    const float* addt  = (const float*)d_in[3];  // [1,256,256,128]
    const float* Wqkvg = (const float*)d_in[4];  // [512,128]
    const float* gbias = (const float*)d_in[5];  // [128]
    const float* Wo    = (const float*)d_in[6];  // [128,128]
    const float* bo    = (const float*)d_in[7];  // [128]
    float* out = (float*)d_out;

    unsigned short* ws = (unsigned short*)d_ws;
    unsigned short* Xb  = ws + XB_OFF;
    unsigned short* Wb  = ws + WB_OFF;
    unsigned short* Wob = ws + WOB_OFF;
    unsigned short* og  = ws + OG_OFF;

    k0_cast<<<4136, 256, 0, stream>>>(X, Wqkvg, Wo, ws);
    k_fused<<<dim3(NH, BB), 256, 0, stream>>>(Xb, Wb, gbias, mask, bias, og);
    k3_proj<<<dim3(BB, 4), 256, 0, stream>>>(og, Wob, bo, addt, out);
}

// Round 14
// 257.407 us; speedup vs baseline: 1.3947x; 1.3947x over previous
//
#include <hip/hip_runtime.h>
#include <math.h>

#define BB 256
#define SS 256
#define NH 4

typedef __attribute__((ext_vector_type(8))) short bfrag;   // 8 bf16 (4 VGPRs)
typedef __attribute__((ext_vector_type(4))) float ffrag;   // 4 fp32 acc

__device__ inline unsigned short f2bf(float x) {
    unsigned u = __float_as_uint(x);
    u += 0x7FFF + ((u >> 16) & 1);          // round-to-nearest-even
    return (unsigned short)(u >> 16);
}
__device__ inline float bf2f(unsigned short h) {
    return __uint_as_float(((unsigned)h) << 16);
}
// Bit-twiddled RNE pack (R4..R13-proven numerics).
__device__ inline unsigned pack2(float a, float b) {
    return (unsigned)f2bf(a) | ((unsigned)f2bf(b) << 16);
}
union FragU { unsigned u[4]; bfrag b; };

// ws layout (bf16 elements):
//   Xb  at 0         [B][S][128]   8388608
//   Wb  at 8388608   [512][128]      65536
//   Wob at 8454144   [128][128]      16384
//   og  at 8470528   [B][S][128]   8388608
#define XB_OFF  0
#define WB_OFF  8388608
#define WOB_OFF 8454144
#define OG_OFF  8470528

// ---------------------------------------------------------------------------
// k0: cast X, W_qkvg, W_o from fp32 to bf16 into workspace. 8 elems/thread.
// ---------------------------------------------------------------------------
__global__ __launch_bounds__(256) void k0_cast(
    const float* __restrict__ X, const float* __restrict__ W,
    const float* __restrict__ Wo, unsigned short* __restrict__ dst)
{
    const int gid = blockIdx.x * 256 + threadIdx.x;
    const int XN8 = 8388608 / 8, WN8 = 65536 / 8, WoN8 = 16384 / 8;
    const float* src;
    size_t soff, doff;
    if (gid < XN8)            { src = X;  soff = (size_t)gid * 8;                 doff = XB_OFF + soff; }
    else if (gid < XN8 + WN8) { src = W;  soff = (size_t)(gid - XN8) * 8;         doff = WB_OFF + soff; }
    else if (gid < XN8 + WN8 + WoN8) { src = Wo; soff = (size_t)(gid - XN8 - WN8) * 8; doff = WOB_OFF + soff; }
    else return;
    const float4 a = *(const float4*)(src + soff);
    const float4 b = *(const float4*)(src + soff + 4);
    unsigned r0 = pack2(a.x, a.y), r1 = pack2(a.z, a.w);
    unsigned r2 = pack2(b.x, b.y), r3 = pack2(b.z, b.w);
    uint4 o; o.x = r0; o.y = r1; o.z = r2; o.w = r3;
    *(uint4*)(dst + doff) = o;
}

// ---------------------------------------------------------------------------
// Fused QKVG projection + attention per (b,h). 256 thr = 4 waves; wave w owns
// s/q rows [64w, 64w+64). 16x16x32 bf16 MFMA layouts:
//   A/B-frag: row = lane&15, k = (lane>>4)*8 + j
//   C/D:      row = (lane>>4)*4 + reg, col = lane&15
//
// R14 = R13's CORRECTNESS-PASSED algorithm with the resource request fixed.
// R13 discovery: __launch_bounds__ arg2=N caps VGPR at 512/(2N) (measured:
// N=2->128, N=3->84, N=4->64). R13's (256,3) self-imposed an 84 cap ->
// 300+ MB spills. Here: (256,2) -> 128 cap (R0-proven spill-free), and the
// +24 persistent VGPRs of Q/G register state are paid for by UN-HOISTING
// Vfr (V frags re-read from LDS per ck inside the PV loop; LDS BW is idle,
// 16 waves/CU of TLP hides the latency).
// LDS: Kb 20480 + Vt 16896 + mask 1024 = 38400 B -> 4 blocks/CU possible
// (4x38.4 = 153.6 <= 160 KB; 16 waves x 128 VGPR = 512/SIMD exactly).
//  - Q: swapped mfma(W,X) -> Q^T in registers; k-permutation pi absorbed in
//    Kb's p(c)-permuted column store (R13-verified).
//  - G: swapped mfma(Wg,X) -> G^T in registers (R13-verified).
// PV keeps R0's proven shuffle form.
// ---------------------------------------------------------------------------
__global__ __launch_bounds__(256, 2) void k_fused(
    const unsigned short* __restrict__ Xb,   // bf16 [B][S][128]
    const unsigned short* __restrict__ Wb,   // bf16 [512][128]
    const float* __restrict__ gbias,         // [128]
    const float* __restrict__ mask,          // [B][S] (k-indexed)
    const float* __restrict__ bias,          // [NH][S][S]
    unsigned short* __restrict__ og)         // bf16 [B][S][128]
{
    const int h = blockIdx.x, b = blockIdx.y;
    const int t = threadIdx.x;
    const int w = t >> 6, lane = t & 63, l15 = lane & 15, quad = lane >> 4;

    __shared__ unsigned short Kb[SS * 40];   // [s][p(c)] stride 40 (pi-permuted cols)
    __shared__ unsigned short Vt[32 * 264];  // [c][s] stride 264
    __shared__ float maskLds[SS];

    maskLds[t] = (mask[b * SS + t] - 1.0f) * 1e9f;

    const float qscale = 0.17677669529663687f;  // 1/sqrt(32)

    // Per-st Q^T B-frags and packed G (named vars; all selects compile-time)
    FragU qa0, qa1, qa2, qa3;
    unsigned g0c0a, g0c0b, g0c1a, g0c1b;
    unsigned g1c0a, g1c0b, g1c1a, g1c1b;
    unsigned g2c0a, g2c0b, g2c1a, g2c1b;
    unsigned g3c0a, g3c0b, g3c1a, g3c1b;

    // ---------------- phase A: QKVG projection for head h ----------------
#pragma unroll
    for (int half = 0; half < 2; ++half) {
        bfrag Wfr[4][4];
#pragma unroll
        for (int f4 = 0; f4 < 4; ++f4) {
            const int floc = (half * 4 + f4) * 16 + l15;            // 0..127
            const int grow = (floc >> 5) * 128 + h * 32 + (floc & 31);
#pragma unroll
            for (int cc = 0; cc < 4; ++cc)
                Wfr[f4][cc] = *(const bfrag*)(Wb + grow * 128 + cc * 32 + quad * 8);
        }
#pragma unroll
        for (int st = 0; st < 4; ++st) {
            const int s = w * 64 + st * 16 + l15;
            bfrag Xfr[4];
#pragma unroll
            for (int cc = 0; cc < 4; ++cc)
                Xfr[cc] = *(const bfrag*)(Xb + (b * SS + s) * 128 + cc * 32 + quad * 8);
#pragma unroll
            for (int f4 = 0; f4 < 4; ++f4) {
                const int ft = half * 4 + f4;
                if (ft < 2) {
                    // ---- Q: swapped mfma -> Q^T (c rows = quad*4+r [+16])
                    ffrag D = {0.f, 0.f, 0.f, 0.f};
#pragma unroll
                    for (int cc = 0; cc < 4; ++cc)
                        D = __builtin_amdgcn_mfma_f32_16x16x32_bf16(Wfr[f4][cc], Xfr[cc], D, 0, 0, 0);
                    const unsigned lo = pack2(D[0] * qscale, D[1] * qscale);
                    const unsigned hi = pack2(D[2] * qscale, D[3] * qscale);
                    FragU* qa = (st == 0) ? &qa0 : (st == 1) ? &qa1 : (st == 2) ? &qa2 : &qa3;
                    if (ft == 0) { qa->u[0] = lo; qa->u[1] = hi; }
                    else         { qa->u[2] = lo; qa->u[3] = hi; }
                } else if (ft < 4) {
                    // ---- K: normal orientation; pi-permuted column store
                    ffrag D = {0.f, 0.f, 0.f, 0.f};
#pragma unroll
                    for (int cc = 0; cc < 4; ++cc)
                        D = __builtin_amdgcn_mfma_f32_16x16x32_bf16(Xfr[cc], Wfr[f4][cc], D, 0, 0, 0);
                    const int c = (ft - 2) * 16 + l15;               // 0..31
                    const int p = ((c & 15) >> 2) * 8 + (c & 3) + ((c >> 4) << 2);
                    const int srow0 = w * 64 + st * 16 + quad * 4;
#pragma unroll
                    for (int r = 0; r < 4; ++r)
                        Kb[(srow0 + r) * 40 + p] = f2bf(D[r]);
                } else if (ft < 6) {
                    // ---- V: normal orientation -> Vt [c][s] (R0 layout)
                    ffrag D = {0.f, 0.f, 0.f, 0.f};
#pragma unroll
                    for (int cc = 0; cc < 4; ++cc)
                        D = __builtin_amdgcn_mfma_f32_16x16x32_bf16(Xfr[cc], Wfr[f4][cc], D, 0, 0, 0);
                    const int fcol = ft * 16 + l15;
                    const int srow0 = w * 64 + st * 16 + quad * 4;
                    const int base = (fcol - 64) * 264 + srow0;
                    *(unsigned*)&Vt[base]     = pack2(D[0], D[1]);
                    *(unsigned*)&Vt[base + 2] = pack2(D[2], D[3]);
                } else {
                    // ---- G: swapped mfma -> G^T (c rows = ch*16+quad*4+r, s col = l15)
                    ffrag D = {0.f, 0.f, 0.f, 0.f};
#pragma unroll
                    for (int cc = 0; cc < 4; ++cc)
                        D = __builtin_amdgcn_mfma_f32_16x16x32_bf16(Wfr[f4][cc], Xfr[cc], D, 0, 0, 0);
                    const int ch = ft - 6;                           // 0,1
                    float gv[4];
#pragma unroll
                    for (int r = 0; r < 4; ++r) {
                        const float gb = gbias[h * 32 + ch * 16 + quad * 4 + r];
                        gv[r] = 1.0f / (1.0f + __expf(-(D[r] + gb)));
                    }
                    const unsigned pa = pack2(gv[0], gv[1]);
                    const unsigned pb = pack2(gv[2], gv[3]);
                    if (st == 0) { if (ch == 0) { g0c0a = pa; g0c0b = pb; } else { g0c1a = pa; g0c1b = pb; } }
                    if (st == 1) { if (ch == 0) { g1c0a = pa; g1c0b = pb; } else { g1c1a = pa; g1c1b = pb; } }
                    if (st == 2) { if (ch == 0) { g2c0a = pa; g2c0b = pb; } else { g2c1a = pa; g2c1b = pb; } }
                    if (st == 3) { if (ch == 0) { g3c0a = pa; g3c0b = pb; } else { g3c1a = pa; g3c1b = pb; } }
                }
            }
        }
    }
    __syncthreads();

    // ---------------- phase B: attention ----------------
    // Vfr intentionally NOT hoisted (R14): re-read from LDS per ck to keep
    // persistent VGPRs under the 128 cap while Q/G live in registers.
    const int srcA = l15 + ((quad & 1) * 2) * 16;
    const int srcB = srcA + 16;
    const bool hi = (quad >> 1) != 0;

    for (int qq = 0; qq < 4; ++qq) {
        const int q = w * 64 + qq * 16 + l15;
        // Q^T B-frag and G pairs from registers (wave-uniform select)
        bfrag Qfr;
        unsigned gc0a, gc0b, gc1a, gc1b;
        if (qq == 0)      { Qfr = qa0.b; gc0a = g0c0a; gc0b = g0c0b; gc1a = g0c1a; gc1b = g0c1b; }
        else if (qq == 1) { Qfr = qa1.b; gc0a = g1c0a; gc0b = g1c0b; gc1a = g1c1a; gc1b = g1c1b; }
        else if (qq == 2) { Qfr = qa2.b; gc0a = g2c0a; gc0b = g2c0b; gc1a = g2c1a; gc1b = g2c1b; }
        else              { Qfr = qa3.b; gc0a = g3c0a; gc0b = g3c0b; gc1a = g3c1a; gc1b = g3c1b; }

        ffrag S[16];
#pragma unroll
        for (int kt = 0; kt < 16; ++kt) {
            const bfrag Kfr = *(const bfrag*)&Kb[(kt * 16 + l15) * 40 + quad * 8];
            const ffrag z = {0.f, 0.f, 0.f, 0.f};
            S[kt] = __builtin_amdgcn_mfma_f32_16x16x32_bf16(Kfr, Qfr, z, 0, 0, 0);
        }

        // + bias + mask; running max (lane owns column q; rows k=kt*16+quad*4+r)
        const float* brow = bias + (h * SS + q) * SS;
        float m = -1e30f;
#pragma unroll
        for (int kt = 0; kt < 16; ++kt) {
            const float4 bv = *(const float4*)(brow + kt * 16 + quad * 4);
            const float4 mv = *(const float4*)(maskLds + kt * 16 + quad * 4);
            S[kt][0] += bv.x + mv.x; S[kt][1] += bv.y + mv.y;
            S[kt][2] += bv.z + mv.z; S[kt][3] += bv.w + mv.w;
            m = fmaxf(m, fmaxf(fmaxf(S[kt][0], S[kt][1]), fmaxf(S[kt][2], S[kt][3])));
        }
        m = fmaxf(m, __shfl_xor(m, 16, 64));
        m = fmaxf(m, __shfl_xor(m, 32, 64));

        float l = 0.f;
        unsigned pk[16][2];   // P packed bf16 pairs (r01, r23), C-layout
#pragma unroll
        for (int kt = 0; kt < 16; ++kt) {
            const float p0 = __expf(S[kt][0] - m);
            const float p1 = __expf(S[kt][1] - m);
            const float p2 = __expf(S[kt][2] - m);
            const float p3 = __expf(S[kt][3] - m);
            l += (p0 + p1) + (p2 + p3);
            pk[kt][0] = pack2(p0, p1);
            pk[kt][1] = pack2(p2, p3);
        }
        l += __shfl_xor(l, 16, 64);
        l += __shfl_xor(l, 32, 64);

        // C-layout -> B-frag transform via cross-quad shuffles (R0-proven).
        ffrag O[2];
        O[0] = (ffrag){0.f, 0.f, 0.f, 0.f};
        O[1] = (ffrag){0.f, 0.f, 0.f, 0.f};
#pragma unroll
        for (int ck = 0; ck < 8; ++ck) {
            const unsigned a0 = (unsigned)__shfl((int)pk[2 * ck][0],     srcA, 64);
            const unsigned b0 = (unsigned)__shfl((int)pk[2 * ck + 1][0], srcA, 64);
            const unsigned a1 = (unsigned)__shfl((int)pk[2 * ck][1],     srcA, 64);
            const unsigned b1 = (unsigned)__shfl((int)pk[2 * ck + 1][1], srcA, 64);
            const unsigned a2 = (unsigned)__shfl((int)pk[2 * ck][0],     srcB, 64);
            const unsigned b2 = (unsigned)__shfl((int)pk[2 * ck + 1][0], srcB, 64);
            const unsigned a3 = (unsigned)__shfl((int)pk[2 * ck][1],     srcB, 64);
            const unsigned b3 = (unsigned)__shfl((int)pk[2 * ck + 1][1], srcB, 64);
            FragU fu;
            fu.u[0] = hi ? b0 : a0;
            fu.u[1] = hi ? b1 : a1;
            fu.u[2] = hi ? b2 : a2;
            fu.u[3] = hi ? b3 : a3;
            const bfrag v0 = *(const bfrag*)&Vt[(l15) * 264 + ck * 32 + quad * 8];
            const bfrag v1 = *(const bfrag*)&Vt[(16 + l15) * 264 + ck * 32 + quad * 8];
            O[0] = __builtin_amdgcn_mfma_f32_16x16x32_bf16(v0, fu.b, O[0], 0, 0, 0);
            O[1] = __builtin_amdgcn_mfma_f32_16x16x32_bf16(v1, fu.b, O[1], 0, 0, 0);
        }

        const float invl = 1.0f / l;
        unsigned* orow = (unsigned*)(og + (b * SS + q) * 128 + h * 32);
#pragma unroll
        for (int ch = 0; ch < 2; ++ch) {
            const unsigned ga = ch ? gc1a : gc0a;
            const unsigned gb2 = ch ? gc1b : gc0b;
            const int c0 = ch * 16 + quad * 4;
            const float v0 = O[ch][0] * invl * bf2f((unsigned short)(ga & 0xffff));
            const float v1 = O[ch][1] * invl * bf2f((unsigned short)(ga >> 16));
            const float v2 = O[ch][2] * invl * bf2f((unsigned short)(gb2 & 0xffff));
            const float v3 = O[ch][3] * invl * bf2f((unsigned short)(gb2 >> 16));
            orow[(c0 >> 1) + 0] = pack2(v0, v1);
            orow[(c0 >> 1) + 1] = pack2(v2, v3);
        }
    }
}

// ---------------------------------------------------------------------------
// k3: out[(s*B + j)*128 + c] = addt[same] + bo[c] + sum_f og[j][s][f]*Wo[c][f]
// R8-passed version: block (j, ih) = 64 s-rows, grid (256,4); og staging
// coalesced; MFMA -> fp32 LDS; coalesced float4 epilogue (half-wave per row).
// ---------------------------------------------------------------------------
__global__ __launch_bounds__(256) void k3_proj(
    const unsigned short* __restrict__ ogb,  // bf16 [B(j)][S(s)][128]
    const unsigned short* __restrict__ Wob,  // bf16 [128][128]
    const float* __restrict__ bo,            // [128]
    const float* __restrict__ addt,          // [S][B][128] view
    float* __restrict__ out)                 // [S][B][128]
{
    const int j = blockIdx.x, ih = blockIdx.y;   // ih: s-chunk of 64 rows
    const int t = threadIdx.x;
    const int w = t >> 6, lane = t & 63, l15 = lane & 15, quad = lane >> 4;

    __shared__ unsigned short OgS[64 * 136];  // [s_loc][f] stride 136, 17.4 KB
    __shared__ float OutS[64 * 132];          // [s_loc][c] stride 132, 33.8 KB

    // stage og[j][ih*64 + ss][0..128) -> LDS (coalesced; 4 threads per row)
    {
        const int ss = t >> 2;                // 0..63
        const int c32 = (t & 3) * 32;         // 0,32,64,96
        const unsigned short* src = ogb + (((size_t)j * SS + ih * 64 + ss) * 128) + c32;
        unsigned short* dst = &OgS[ss * 136 + c32];
#pragma unroll
        for (int u = 0; u < 4; ++u)
            *(uint4*)(dst + u * 8) = *(const uint4*)(src + u * 8);
    }

    // per-wave Wo B-frags: c rows (w*2+ctl)*16 + l15
    bfrag Wfr[2][4];
#pragma unroll
    for (int ctl = 0; ctl < 2; ++ctl) {
        const int crow = (w * 2 + ctl) * 16 + l15;
#pragma unroll
        for (int cc = 0; cc < 4; ++cc)
            Wfr[ctl][cc] = *(const bfrag*)(Wob + crow * 128 + cc * 32 + quad * 8);
    }
    const float bo0 = bo[(w * 2 + 0) * 16 + l15];
    const float bo1 = bo[(w * 2 + 1) * 16 + l15];

    __syncthreads();

#pragma unroll
    for (int jt = 0; jt < 4; ++jt) {
        bfrag Ab[4];
#pragma unroll
        for (int cc = 0; cc < 4; ++cc)
            Ab[cc] = *(const bfrag*)&OgS[(jt * 16 + l15) * 136 + cc * 32 + quad * 8];

        ffrag D0 = {0.f, 0.f, 0.f, 0.f};
        ffrag D1 = {0.f, 0.f, 0.f, 0.f};
#pragma unroll
        for (int cc = 0; cc < 4; ++cc) {
            D0 = __builtin_amdgcn_mfma_f32_16x16x32_bf16(Ab[cc], Wfr[0][cc], D0, 0, 0, 0);
            D1 = __builtin_amdgcn_mfma_f32_16x16x32_bf16(Ab[cc], Wfr[1][cc], D1, 0, 0, 0);
        }

        // D (+bo) -> LDS; C/D layout: row = quad*4+r (within 16), col = l15
        const int c0 = (w * 2 + 0) * 16 + l15;
        const int c1 = (w * 2 + 1) * 16 + l15;
#pragma unroll
        for (int r = 0; r < 4; ++r) {
            const int row = jt * 16 + quad * 4 + r;
            OutS[row * 132 + c0] = D0[r] + bo0;
            OutS[row * 132 + c1] = D1[r] + bo1;
        }
    }
    __syncthreads();

    // coalesced epilogue: half-wave per s-row, float4 ld/add/st
    {
        const int c4 = lane & 31;             // float4 index within the row
        const int rsub = t >> 5;              // 0..7 (wave, half)
#pragma unroll
        for (int v = 0; v < 8; ++v) {
            const int row = v * 8 + rsub;     // 0..63
            const int s = ih * 64 + row;
            const size_t off = ((size_t)s * BB + j) * 128 + c4 * 4;
            const float4 av = *(const float4*)(addt + off);
            const float4 dv = *(const float4*)&OutS[row * 132 + c4 * 4];
            float4 ov;
            ov.x = dv.x + av.x; ov.y = dv.y + av.y;
            ov.z = dv.z + av.z; ov.w = dv.w + av.w;
            *(float4*)(out + off) = ov;
        }
    }
}

extern "C" void kernel_launch(void* const* d_in, const int* in_sizes, int n_in,
                              void* d_out, int out_size, void* d_ws, size_t ws_size,
                              hipStream_t stream) {
    const float* X     = (const float*)d_in[0];  // input_qkv [1,256,256,128]
    const float* mask  = (const float*)d_in[1];  // [1,256,1,1,256]
    const float* bias  = (const float*)d_in[2];  // [1,1,4,256,256]
    const float* addt  = (const float*)d_in[3];  // [1,256,256,128]
    const float* Wqkvg = (const float*)d_in[4];  // [512,128]
    const float* gbias = (const float*)d_in[5];  // [128]
    const float* Wo    = (const float*)d_in[6];  // [128,128]
    const float* bo    = (const float*)d_in[7];  // [128]
    float* out = (float*)d_out;

    unsigned short* ws = (unsigned short*)d_ws;
    unsigned short* Xb  = ws + XB_OFF;
    unsigned short* Wb  = ws + WB_OFF;
    unsigned short* Wob = ws + WOB_OFF;
    unsigned short* og  = ws + OG_OFF;

    k0_cast<<<4136, 256, 0, stream>>>(X, Wqkvg, Wo, ws);
    k_fused<<<dim3(NH, BB), 256, 0, stream>>>(Xb, Wb, gbias, mask, bias, og);
    k3_proj<<<dim3(BB, 4), 256, 0, stream>>>(og, Wob, bo, addt, out);
}

// Round 15
// 254.490 us; speedup vs baseline: 1.4107x; 1.0115x over previous
//
#include <hip/hip_runtime.h>
#include <math.h>

#define BB 256
#define SS 256
#define NH 4

typedef __attribute__((ext_vector_type(8))) short bfrag;   // 8 bf16 (4 VGPRs)
typedef __attribute__((ext_vector_type(4))) float ffrag;   // 4 fp32 acc

__device__ inline unsigned short f2bf(float x) {
    unsigned u = __float_as_uint(x);
    u += 0x7FFF + ((u >> 16) & 1);          // round-to-nearest-even
    return (unsigned short)(u >> 16);
}
__device__ inline float bf2f(unsigned short h) {
    return __uint_as_float(((unsigned)h) << 16);
}
// Bit-twiddled RNE pack (R4..R14-proven numerics).
__device__ inline unsigned pack2(float a, float b) {
    return (unsigned)f2bf(a) | ((unsigned)f2bf(b) << 16);
}
union FragU { unsigned u[4]; bfrag b; };

// ws layout (bf16 elements):
//   Xb  at 0         [B][S][128]   8388608
//   Wb  at 8388608   [512][128]      65536
//   Wob at 8454144   [128][128]      16384
//   og  at 8470528   [B][S][128]   8388608
#define XB_OFF  0
#define WB_OFF  8388608
#define WOB_OFF 8454144
#define OG_OFF  8470528

// ---------------------------------------------------------------------------
// k0: cast X, W_qkvg, W_o from fp32 to bf16 into workspace. 8 elems/thread.
// ---------------------------------------------------------------------------
__global__ __launch_bounds__(256) void k0_cast(
    const float* __restrict__ X, const float* __restrict__ W,
    const float* __restrict__ Wo, unsigned short* __restrict__ dst)
{
    const int gid = blockIdx.x * 256 + threadIdx.x;
    const int XN8 = 8388608 / 8, WN8 = 65536 / 8, WoN8 = 16384 / 8;
    const float* src;
    size_t soff, doff;
    if (gid < XN8)            { src = X;  soff = (size_t)gid * 8;                 doff = XB_OFF + soff; }
    else if (gid < XN8 + WN8) { src = W;  soff = (size_t)(gid - XN8) * 8;         doff = WB_OFF + soff; }
    else if (gid < XN8 + WN8 + WoN8) { src = Wo; soff = (size_t)(gid - XN8 - WN8) * 8; doff = WOB_OFF + soff; }
    else return;
    const float4 a = *(const float4*)(src + soff);
    const float4 b = *(const float4*)(src + soff + 4);
    unsigned r0 = pack2(a.x, a.y), r1 = pack2(a.z, a.w);
    unsigned r2 = pack2(b.x, b.y), r3 = pack2(b.z, b.w);
    uint4 o; o.x = r0; o.y = r1; o.z = r2; o.w = r3;
    *(uint4*)(dst + doff) = o;
}

// ---------------------------------------------------------------------------
// Fused QKVG projection + attention per (b,h). 256 thr = 4 waves; wave w owns
// s/q rows [64w, 64w+64). 16x16x32 bf16 MFMA layouts:
//   A/B-frag: row = lane&15, k = (lane>>4)*8 + j
//   C/D:      row = (lane>>4)*4 + reg, col = lane&15
//
// R15 = R13's correctness-proven algorithm with REGISTER PEAK reduced so the
// 128-VGPR cap ((256,2); measured law: cap = 256/arg2) holds WITHOUT spills
// (R14: peak > 128 -> 77 MB scratch, occupancy stuck):
//  1. Phase A: loop order half->f4->st. Wfr working set [4][4]->[4]
//     (64->16 regs); Xfr reloaded per f4 (L1-hit, block's X tile = 16 KB).
//  2. Phase B: ONLINE SOFTMAX over 4 chunks x 4 kt: S[16]->S[4] (64->16),
//     running (m,l), O *= exp(m - m_new) per chunk (flash identity; fp32
//     rescale noise << 0.107 absmax budget). PV shuffles/MFMAs unchanged in
//     total, redistributed per-chunk. Vfr stays unhoisted (R14).
// Proven pieces verbatim: swapped-Q/G + pi-permuted Kb (R13, passed), PV
// shuffle form (R0), k0/k3 (R8).
// LDS: Kb 20480 + Vt 16896 + mask 1024 = 38400 B -> 4 blocks/CU (153.6 KB);
// 16 waves x 128 VGPR = 512/SIMD exactly.
// ---------------------------------------------------------------------------
__global__ __launch_bounds__(256, 2) void k_fused(
    const unsigned short* __restrict__ Xb,   // bf16 [B][S][128]
    const unsigned short* __restrict__ Wb,   // bf16 [512][128]
    const float* __restrict__ gbias,         // [128]
    const float* __restrict__ mask,          // [B][S] (k-indexed)
    const float* __restrict__ bias,          // [NH][S][S]
    unsigned short* __restrict__ og)         // bf16 [B][S][128]
{
    const int h = blockIdx.x, b = blockIdx.y;
    const int t = threadIdx.x;
    const int w = t >> 6, lane = t & 63, l15 = lane & 15, quad = lane >> 4;

    __shared__ unsigned short Kb[SS * 40];   // [s][p(c)] stride 40 (pi-permuted cols)
    __shared__ unsigned short Vt[32 * 264];  // [c][s] stride 264
    __shared__ float maskLds[SS];

    maskLds[t] = (mask[b * SS + t] - 1.0f) * 1e9f;

    const float qscale = 0.17677669529663687f;  // 1/sqrt(32)

    // Per-st Q^T B-frags and packed G (named vars; all selects compile-time)
    FragU qa0, qa1, qa2, qa3;
    unsigned g0c0a, g0c0b, g0c1a, g0c1b;
    unsigned g1c0a, g1c0b, g1c1a, g1c1b;
    unsigned g2c0a, g2c0b, g2c1a, g2c1b;
    unsigned g3c0a, g3c0b, g3c1a, g3c1b;

    // ---------------- phase A: QKVG projection for head h ----------------
    // R15 order: half -> f4 (Wfr[4], 16 regs) -> st (Xfr[4] reload, L1-hit)
#pragma unroll
    for (int half = 0; half < 2; ++half) {
#pragma unroll
        for (int f4 = 0; f4 < 4; ++f4) {
            const int ft = half * 4 + f4;
            const int floc = ft * 16 + l15;                         // 0..127
            const int grow = (floc >> 5) * 128 + h * 32 + (floc & 31);
            bfrag Wfr[4];
#pragma unroll
            for (int cc = 0; cc < 4; ++cc)
                Wfr[cc] = *(const bfrag*)(Wb + grow * 128 + cc * 32 + quad * 8);
#pragma unroll
            for (int st = 0; st < 4; ++st) {
                const int s = w * 64 + st * 16 + l15;
                bfrag Xfr[4];
#pragma unroll
                for (int cc = 0; cc < 4; ++cc)
                    Xfr[cc] = *(const bfrag*)(Xb + (b * SS + s) * 128 + cc * 32 + quad * 8);
                if (ft < 2) {
                    // ---- Q: swapped mfma -> Q^T (R13-proven)
                    ffrag D = {0.f, 0.f, 0.f, 0.f};
#pragma unroll
                    for (int cc = 0; cc < 4; ++cc)
                        D = __builtin_amdgcn_mfma_f32_16x16x32_bf16(Wfr[cc], Xfr[cc], D, 0, 0, 0);
                    const unsigned lo = pack2(D[0] * qscale, D[1] * qscale);
                    const unsigned hi = pack2(D[2] * qscale, D[3] * qscale);
                    FragU* qa = (st == 0) ? &qa0 : (st == 1) ? &qa1 : (st == 2) ? &qa2 : &qa3;
                    if (ft == 0) { qa->u[0] = lo; qa->u[1] = hi; }
                    else         { qa->u[2] = lo; qa->u[3] = hi; }
                } else if (ft < 4) {
                    // ---- K: normal orientation; pi-permuted column store
                    ffrag D = {0.f, 0.f, 0.f, 0.f};
#pragma unroll
                    for (int cc = 0; cc < 4; ++cc)
                        D = __builtin_amdgcn_mfma_f32_16x16x32_bf16(Xfr[cc], Wfr[cc], D, 0, 0, 0);
                    const int c = (ft - 2) * 16 + l15;               // 0..31
                    const int p = ((c & 15) >> 2) * 8 + (c & 3) + ((c >> 4) << 2);
                    const int srow0 = w * 64 + st * 16 + quad * 4;
#pragma unroll
                    for (int r = 0; r < 4; ++r)
                        Kb[(srow0 + r) * 40 + p] = f2bf(D[r]);
                } else if (ft < 6) {
                    // ---- V: normal orientation -> Vt [c][s] (R0 layout)
                    ffrag D = {0.f, 0.f, 0.f, 0.f};
#pragma unroll
                    for (int cc = 0; cc < 4; ++cc)
                        D = __builtin_amdgcn_mfma_f32_16x16x32_bf16(Xfr[cc], Wfr[cc], D, 0, 0, 0);
                    const int fcol = ft * 16 + l15;
                    const int srow0 = w * 64 + st * 16 + quad * 4;
                    const int base = (fcol - 64) * 264 + srow0;
                    *(unsigned*)&Vt[base]     = pack2(D[0], D[1]);
                    *(unsigned*)&Vt[base + 2] = pack2(D[2], D[3]);
                } else {
                    // ---- G: swapped mfma -> G^T in registers (R13-proven)
                    ffrag D = {0.f, 0.f, 0.f, 0.f};
#pragma unroll
                    for (int cc = 0; cc < 4; ++cc)
                        D = __builtin_amdgcn_mfma_f32_16x16x32_bf16(Wfr[cc], Xfr[cc], D, 0, 0, 0);
                    const int ch = ft - 6;                           // 0,1
                    float gv[4];
#pragma unroll
                    for (int r = 0; r < 4; ++r) {
                        const float gb = gbias[h * 32 + ch * 16 + quad * 4 + r];
                        gv[r] = 1.0f / (1.0f + __expf(-(D[r] + gb)));
                    }
                    const unsigned pa = pack2(gv[0], gv[1]);
                    const unsigned pb = pack2(gv[2], gv[3]);
                    if (st == 0) { if (ch == 0) { g0c0a = pa; g0c0b = pb; } else { g0c1a = pa; g0c1b = pb; } }
                    if (st == 1) { if (ch == 0) { g1c0a = pa; g1c0b = pb; } else { g1c1a = pa; g1c1b = pb; } }
                    if (st == 2) { if (ch == 0) { g2c0a = pa; g2c0b = pb; } else { g2c1a = pa; g2c1b = pb; } }
                    if (st == 3) { if (ch == 0) { g3c0a = pa; g3c0b = pb; } else { g3c1a = pa; g3c1b = pb; } }
                }
            }
        }
    }
    __syncthreads();

    // ---------------- phase B: attention (online softmax, 4 chunks) -------
    const int srcA = l15 + ((quad & 1) * 2) * 16;
    const int srcB = srcA + 16;
    const bool hi = (quad >> 1) != 0;

    for (int qq = 0; qq < 4; ++qq) {
        const int q = w * 64 + qq * 16 + l15;
        bfrag Qfr;
        unsigned gc0a, gc0b, gc1a, gc1b;
        if (qq == 0)      { Qfr = qa0.b; gc0a = g0c0a; gc0b = g0c0b; gc1a = g0c1a; gc1b = g0c1b; }
        else if (qq == 1) { Qfr = qa1.b; gc0a = g1c0a; gc0b = g1c0b; gc1a = g1c1a; gc1b = g1c1b; }
        else if (qq == 2) { Qfr = qa2.b; gc0a = g2c0a; gc0b = g2c0b; gc1a = g2c1a; gc1b = g2c1b; }
        else              { Qfr = qa3.b; gc0a = g3c0a; gc0b = g3c0b; gc1a = g3c1a; gc1b = g3c1b; }

        const float* brow = bias + (h * SS + q) * SS;
        ffrag O[2];
        O[0] = (ffrag){0.f, 0.f, 0.f, 0.f};
        O[1] = (ffrag){0.f, 0.f, 0.f, 0.f};
        float m = -1e30f, l = 0.f;

#pragma unroll
        for (int c = 0; c < 4; ++c) {
            // S for this chunk (kt = 4c..4c+3)
            ffrag S[4];
#pragma unroll
            for (int i = 0; i < 4; ++i) {
                const int kt = 4 * c + i;
                const bfrag Kfr = *(const bfrag*)&Kb[(kt * 16 + l15) * 40 + quad * 8];
                const ffrag z = {0.f, 0.f, 0.f, 0.f};
                S[i] = __builtin_amdgcn_mfma_f32_16x16x32_bf16(Kfr, Qfr, z, 0, 0, 0);
            }
            // + bias + mask; chunk max
            float cm = -1e30f;
#pragma unroll
            for (int i = 0; i < 4; ++i) {
                const int kt = 4 * c + i;
                const float4 bv = *(const float4*)(brow + kt * 16 + quad * 4);
                const float4 mv = *(const float4*)(maskLds + kt * 16 + quad * 4);
                S[i][0] += bv.x + mv.x; S[i][1] += bv.y + mv.y;
                S[i][2] += bv.z + mv.z; S[i][3] += bv.w + mv.w;
                cm = fmaxf(cm, fmaxf(fmaxf(S[i][0], S[i][1]), fmaxf(S[i][2], S[i][3])));
            }
            cm = fmaxf(cm, __shfl_xor(cm, 16, 64));
            cm = fmaxf(cm, __shfl_xor(cm, 32, 64));
            const float mnew = fmaxf(m, cm);
            const float scale = __expf(m - mnew);   // 0 on first chunk
            O[0][0] *= scale; O[0][1] *= scale; O[0][2] *= scale; O[0][3] *= scale;
            O[1][0] *= scale; O[1][1] *= scale; O[1][2] *= scale; O[1][3] *= scale;
            l *= scale;

            unsigned pk[4][2];
#pragma unroll
            for (int i = 0; i < 4; ++i) {
                const float p0 = __expf(S[i][0] - mnew);
                const float p1 = __expf(S[i][1] - mnew);
                const float p2 = __expf(S[i][2] - mnew);
                const float p3 = __expf(S[i][3] - mnew);
                l += (p0 + p1) + (p2 + p3);
                pk[i][0] = pack2(p0, p1);
                pk[i][1] = pack2(p2, p3);
            }

            // PV for this chunk: global ck = 2c + ck2; pk local index 2*ck2
#pragma unroll
            for (int ck2 = 0; ck2 < 2; ++ck2) {
                const int ck = 2 * c + ck2;
                const unsigned a0 = (unsigned)__shfl((int)pk[2 * ck2][0],     srcA, 64);
                const unsigned b0 = (unsigned)__shfl((int)pk[2 * ck2 + 1][0], srcA, 64);
                const unsigned a1 = (unsigned)__shfl((int)pk[2 * ck2][1],     srcA, 64);
                const unsigned b1 = (unsigned)__shfl((int)pk[2 * ck2 + 1][1], srcA, 64);
                const unsigned a2 = (unsigned)__shfl((int)pk[2 * ck2][0],     srcB, 64);
                const unsigned b2 = (unsigned)__shfl((int)pk[2 * ck2 + 1][0], srcB, 64);
                const unsigned a3 = (unsigned)__shfl((int)pk[2 * ck2][1],     srcB, 64);
                const unsigned b3 = (unsigned)__shfl((int)pk[2 * ck2 + 1][1], srcB, 64);
                FragU fu;
                fu.u[0] = hi ? b0 : a0;
                fu.u[1] = hi ? b1 : a1;
                fu.u[2] = hi ? b2 : a2;
                fu.u[3] = hi ? b3 : a3;
                const bfrag v0 = *(const bfrag*)&Vt[(l15) * 264 + ck * 32 + quad * 8];
                const bfrag v1 = *(const bfrag*)&Vt[(16 + l15) * 264 + ck * 32 + quad * 8];
                O[0] = __builtin_amdgcn_mfma_f32_16x16x32_bf16(v0, fu.b, O[0], 0, 0, 0);
                O[1] = __builtin_amdgcn_mfma_f32_16x16x32_bf16(v1, fu.b, O[1], 0, 0, 0);
            }
            m = mnew;
        }

        l += __shfl_xor(l, 16, 64);
        l += __shfl_xor(l, 32, 64);
        const float invl = 1.0f / l;
        unsigned* orow = (unsigned*)(og + (b * SS + q) * 128 + h * 32);
#pragma unroll
        for (int ch = 0; ch < 2; ++ch) {
            const unsigned ga = ch ? gc1a : gc0a;
            const unsigned gb2 = ch ? gc1b : gc0b;
            const int c0 = ch * 16 + quad * 4;
            const float v0 = O[ch][0] * invl * bf2f((unsigned short)(ga & 0xffff));
            const float v1 = O[ch][1] * invl * bf2f((unsigned short)(ga >> 16));
            const float v2 = O[ch][2] * invl * bf2f((unsigned short)(gb2 & 0xffff));
            const float v3 = O[ch][3] * invl * bf2f((unsigned short)(gb2 >> 16));
            orow[(c0 >> 1) + 0] = pack2(v0, v1);
            orow[(c0 >> 1) + 1] = pack2(v2, v3);
        }
    }
}

// ---------------------------------------------------------------------------
// k3: out[(s*B + j)*128 + c] = addt[same] + bo[c] + sum_f og[j][s][f]*Wo[c][f]
// R8-passed version: block (j, ih) = 64 s-rows, grid (256,4); og staging
// coalesced; MFMA -> fp32 LDS; coalesced float4 epilogue (half-wave per row).
// ---------------------------------------------------------------------------
__global__ __launch_bounds__(256) void k3_proj(
    const unsigned short* __restrict__ ogb,  // bf16 [B(j)][S(s)][128]
    const unsigned short* __restrict__ Wob,  // bf16 [128][128]
    const float* __restrict__ bo,            // [128]
    const float* __restrict__ addt,          // [S][B][128] view
    float* __restrict__ out)                 // [S][B][128]
{
    const int j = blockIdx.x, ih = blockIdx.y;   // ih: s-chunk of 64 rows
    const int t = threadIdx.x;
    const int w = t >> 6, lane = t & 63, l15 = lane & 15, quad = lane >> 4;

    __shared__ unsigned short OgS[64 * 136];  // [s_loc][f] stride 136, 17.4 KB
    __shared__ float OutS[64 * 132];          // [s_loc][c] stride 132, 33.8 KB

    // stage og[j][ih*64 + ss][0..128) -> LDS (coalesced; 4 threads per row)
    {
        const int ss = t >> 2;                // 0..63
        const int c32 = (t & 3) * 32;         // 0,32,64,96
        const unsigned short* src = ogb + (((size_t)j * SS + ih * 64 + ss) * 128) + c32;
        unsigned short* dst = &OgS[ss * 136 + c32];
#pragma unroll
        for (int u = 0; u < 4; ++u)
            *(uint4*)(dst + u * 8) = *(const uint4*)(src + u * 8);
    }

    // per-wave Wo B-frags: c rows (w*2+ctl)*16 + l15
    bfrag Wfr[2][4];
#pragma unroll
    for (int ctl = 0; ctl < 2; ++ctl) {
        const int crow = (w * 2 + ctl) * 16 + l15;
#pragma unroll
        for (int cc = 0; cc < 4; ++cc)
            Wfr[ctl][cc] = *(const bfrag*)(Wob + crow * 128 + cc * 32 + quad * 8);
    }
    const float bo0 = bo[(w * 2 + 0) * 16 + l15];
    const float bo1 = bo[(w * 2 + 1) * 16 + l15];

    __syncthreads();

#pragma unroll
    for (int jt = 0; jt < 4; ++jt) {
        bfrag Ab[4];
#pragma unroll
        for (int cc = 0; cc < 4; ++cc)
            Ab[cc] = *(const bfrag*)&OgS[(jt * 16 + l15) * 136 + cc * 32 + quad * 8];

        ffrag D0 = {0.f, 0.f, 0.f, 0.f};
        ffrag D1 = {0.f, 0.f, 0.f, 0.f};
#pragma unroll
        for (int cc = 0; cc < 4; ++cc) {
            D0 = __builtin_amdgcn_mfma_f32_16x16x32_bf16(Ab[cc], Wfr[0][cc], D0, 0, 0, 0);
            D1 = __builtin_amdgcn_mfma_f32_16x16x32_bf16(Ab[cc], Wfr[1][cc], D1, 0, 0, 0);
        }

        // D (+bo) -> LDS; C/D layout: row = quad*4+r (within 16), col = l15
        const int c0 = (w * 2 + 0) * 16 + l15;
        const int c1 = (w * 2 + 1) * 16 + l15;
#pragma unroll
        for (int r = 0; r < 4; ++r) {
            const int row = jt * 16 + quad * 4 + r;
            OutS[row * 132 + c0] = D0[r] + bo0;
            OutS[row * 132 + c1] = D1[r] + bo1;
        }
    }
    __syncthreads();

    // coalesced epilogue: half-wave per s-row, float4 ld/add/st
    {
        const int c4 = lane & 31;             // float4 index within the row
        const int rsub = t >> 5;              // 0..7 (wave, half)
#pragma unroll
        for (int v = 0; v < 8; ++v) {
            const int row = v * 8 + rsub;     // 0..63
            const int s = ih * 64 + row;
            const size_t off = ((size_t)s * BB + j) * 128 + c4 * 4;
            const float4 av = *(const float4*)(addt + off);
            const float4 dv = *(const float4*)&OutS[row * 132 + c4 * 4];
            float4 ov;
            ov.x = dv.x + av.x; ov.y = dv.y + av.y;
            ov.z = dv.z + av.z; ov.w = dv.w + av.w;
            *(float4*)(out + off) = ov;
        }
    }
}

extern "C" void kernel_launch(void* const* d_in, const int* in_sizes, int n_in,
                              void* d_out, int out_size, void* d_ws, size_t ws_size,
                              hipStream_t stream) {
    const float* X     = (const float*)d_in[0];  // input_qkv [1,256,256,128]
    const float* mask  = (const float*)d_in[1];  // [1,256,1,1,256]
    const float* bias  = (const float*)d_in[2];  // [1,1,4,256,256]
    const float* addt  = (const float*)d_in[3];  // [1,256,256,128]
    const float* Wqkvg = (const float*)d_in[4];  // [512,128]
    const float* gbias = (const float*)d_in[5];  // [128]
    const float* Wo    = (const float*)d_in[6];  // [128,128]
    const float* bo    = (const float*)d_in[7];  // [128]
    float* out = (float*)d_out;

    unsigned short* ws = (unsigned short*)d_ws;
    unsigned short* Xb  = ws + XB_OFF;
    unsigned short* Wb  = ws + WB_OFF;
    unsigned short* Wob = ws + WOB_OFF;
    unsigned short* og  = ws + OG_OFF;

    k0_cast<<<4136, 256, 0, stream>>>(X, Wqkvg, Wo, ws);
    k_fused<<<dim3(NH, BB), 256, 0, stream>>>(Xb, Wb, gbias, mask, bias, og);
    k3_proj<<<dim3(BB, 4), 256, 0, stream>>>(og, Wob, bo, addt, out);
}